// Round 4
// baseline (1633.143 us; speedup 1.0000x reference)
//
#include <hip/hip_runtime.h>
#include <hip/hip_bf16.h>

#define NN 50000
#define NE 400000

// ---- workspace layout (bytes) ----
static const size_t OFF_NPJ    = 0;                       // [NN,256] f32 = 51,200,000
static const size_t OFF_ALPHA  = 51200000;                // [NE,4]   f32 =  6,400,000
static const size_t OFF_SEGMAX = 57600000;                // [NN,4]  u32 =     800,000
static const size_t OFF_SEGSUM = 58400000;                // [NN,4]  f32 =     800,000
static const size_t OFF_BN     = 59200000;                // 16 f32 + flag =      256
static const size_t OFF_AGGR   = 59200256;                // [NN,64] f32 = 12,800,000
static const size_t OFF_IDX32  = 72000256;                // [2,NE] i32  =  3,200,000
static const size_t OFF_OUTJ   = 75200256;                // [NE,256] bf16 = 204,800,000
static const size_t Z_SZ       = OFF_IDX32 - OFF_SEGMAX;  // zeroed each call
static const size_t NEED_STORE = OFF_OUTJ + (size_t)NE * 256 * 2;

__device__ __forceinline__ float softplusf(float x) {
  return fmaxf(x, 0.0f) + log1pf(expf(-fabsf(x)));
}

// ---------- pass A: detect whether edge_index buffer is int64 (odd words all 0)
__global__ __launch_bounds__(256)
void k_idx_detect(const unsigned* __restrict__ src, unsigned* __restrict__ flag)
{
  int t = blockIdx.x * 256 + threadIdx.x;            // t in [0, 400000)
  unsigned v = (t < NE) ? src[2 * t + 1] : 0u;       // odd words of first 800000 words
  if (__any(v != 0) ) { if ((threadIdx.x & 63) == 0) atomicOr(flag, 1u); }
}

// ---------- pass B: convert edge_index to int32 (handles int32 or int64 source)
__global__ __launch_bounds__(256)
void k_idx_cvt(const unsigned* __restrict__ src, const unsigned* __restrict__ flag,
               int* __restrict__ dst)
{
  int e = blockIdx.x * 256 + threadIdx.x;            // e in [0, 800000)
  unsigned f = *flag;                                 // f==1 -> src was int32
  dst[e] = (int)(f ? src[e] : src[2 * e]);
}

// ---------- pass 0: node_proj[n,c] = sum_k x[n,k] * W[k,c]  (top 64 rows of W)
__global__ __launch_bounds__(256, 2)
void k_node_proj(const float* __restrict__ x, const float* __restrict__ W,
                 float* __restrict__ npj)
{
  __shared__ float Wl[64][256];
  for (int t = threadIdx.x; t < 64 * 256; t += 256) Wl[t >> 8][t & 255] = W[t];
  __syncthreads();
  int wave = threadIdx.x >> 6, lane = threadIdx.x & 63;
  int node = blockIdx.x * 4 + wave;
  float xv = x[(size_t)node * 64 + lane];
  float a0 = 0, a1 = 0, a2 = 0, a3 = 0;
  for (int k = 0; k < 64; ++k) {
    float xk = __shfl(xv, k);
    a0 = fmaf(xk, Wl[k][lane      ], a0);
    a1 = fmaf(xk, Wl[k][lane +  64], a1);
    a2 = fmaf(xk, Wl[k][lane + 128], a2);
    a3 = fmaf(xk, Wl[k][lane + 192], a3);
  }
  size_t b = (size_t)node * 256 + lane;
  npj[b] = a0; npj[b + 64] = a1; npj[b + 128] = a2; npj[b + 192] = a3;
}

// ---------- pass 1: per-edge tea = ea @ W_bot, alpha_raw = softplus(att-dot), BN stats
template<int STORE>
__global__ __launch_bounds__(256, 2)
void k_edge_alpha(const float* __restrict__ ea, const float* __restrict__ W,
                  const float* __restrict__ att, const int* __restrict__ idx,
                  const float* __restrict__ npj, float* __restrict__ alpha,
                  float* __restrict__ bnst, __hip_bfloat16* __restrict__ outj)
{
  __shared__ float Wl[64][256];
  __shared__ float attl[4][128];
  __shared__ float red[4][8];
  for (int t = threadIdx.x; t < 64 * 256; t += 256) Wl[t >> 8][t & 255] = W[16384 + t];
  for (int t = threadIdx.x; t < 512; t += 256) attl[t >> 7][t & 127] = att[t];
  __syncthreads();
  int wave = threadIdx.x >> 6, lane = threadIdx.x & 63;
  float bs0 = 0, bs1 = 0, bs2 = 0, bs3 = 0, ss0 = 0, ss1 = 0, ss2 = 0, ss3 = 0;
  int ebase = blockIdx.x * 64 + wave * 16;
  for (int g = 0; g < 4; ++g) {
    int e0 = ebase + g * 4;
    float ear[4]; int ii[4], jj[4];
#pragma unroll
    for (int e = 0; e < 4; ++e) {
      ear[e] = ea[(size_t)(e0 + e) * 64 + lane];
      ii[e] = idx[e0 + e]; jj[e] = idx[NE + e0 + e];
    }
    float npi[4][4], npv[4][4];
#pragma unroll
    for (int e = 0; e < 4; ++e) {
      size_t bi = (size_t)ii[e] * 256 + lane, bj = (size_t)jj[e] * 256 + lane;
#pragma unroll
      for (int q = 0; q < 4; ++q) { npi[e][q] = npj[bi + 64 * q]; npv[e][q] = npj[bj + 64 * q]; }
    }
    float tea[4][4] = {};
    for (int k = 0; k < 64; ++k) {
      float w0 = Wl[k][lane], w1 = Wl[k][lane + 64], w2 = Wl[k][lane + 128], w3 = Wl[k][lane + 192];
#pragma unroll
      for (int e = 0; e < 4; ++e) {
        float a = __shfl(ear[e], k);
        tea[e][0] = fmaf(a, w0, tea[e][0]);
        tea[e][1] = fmaf(a, w1, tea[e][1]);
        tea[e][2] = fmaf(a, w2, tea[e][2]);
        tea[e][3] = fmaf(a, w3, tea[e][3]);
      }
    }
#pragma unroll
    for (int e = 0; e < 4; ++e) {
      float pa[4];
#pragma unroll
      for (int q = 0; q < 4; ++q) {
        float oi = softplusf(npi[e][q] + tea[e][q]);
        float oj = softplusf(npv[e][q] + tea[e][q]);
        if (STORE) outj[(size_t)(e0 + e) * 256 + lane + 64 * q] = __float2bfloat16(oj);
        pa[q] = fmaf(oi, attl[q][lane], oj * attl[q][64 + lane]);
      }
#pragma unroll
      for (int m = 32; m; m >>= 1) {
        pa[0] += __shfl_xor(pa[0], m);
        pa[1] += __shfl_xor(pa[1], m);
        pa[2] += __shfl_xor(pa[2], m);
        pa[3] += __shfl_xor(pa[3], m);
      }
      float a0 = softplusf(pa[0]), a1 = softplusf(pa[1]);
      float a2 = softplusf(pa[2]), a3 = softplusf(pa[3]);
      if (lane == 0) {
        float4 v = make_float4(a0, a1, a2, a3);
        *reinterpret_cast<float4*>(&alpha[(size_t)(e0 + e) * 4]) = v;
      }
      bs0 += a0; bs1 += a1; bs2 += a2; bs3 += a3;
      ss0 = fmaf(a0, a0, ss0); ss1 = fmaf(a1, a1, ss1);
      ss2 = fmaf(a2, a2, ss2); ss3 = fmaf(a3, a3, ss3);
    }
  }
  if (lane == 0) {
    red[wave][0] = bs0; red[wave][1] = bs1; red[wave][2] = bs2; red[wave][3] = bs3;
    red[wave][4] = ss0; red[wave][5] = ss1; red[wave][6] = ss2; red[wave][7] = ss3;
  }
  __syncthreads();
  if (threadIdx.x < 8) {
    float s = red[0][threadIdx.x] + red[1][threadIdx.x] + red[2][threadIdx.x] + red[3][threadIdx.x];
    atomicAdd(&bnst[threadIdx.x], s);
  }
}

// ---------- pass 2: BN finalize (mu, rstd*gamma)
__global__ void k_bn_fin(float* __restrict__ bnst, const float* __restrict__ gamma)
{
  int q = threadIdx.x;
  if (q < 4) {
    float mu = bnst[q] * (1.0f / NE);
    float var = bnst[4 + q] * (1.0f / NE) - mu * mu;
    bnst[8 + q] = mu;
    bnst[12 + q] = rsqrtf(var + 1e-5f) * gamma[q];
  }
}

// ---------- pass 3: alpha = softplus(BN(alpha)); segment max (uint trick, values > 0)
__global__ __launch_bounds__(256)
void k_bn_max(float* __restrict__ alpha, const int* __restrict__ idx,
              const float* __restrict__ bnst, const float* __restrict__ beta,
              unsigned* __restrict__ segmax)
{
  int e = blockIdx.x * 256 + threadIdx.x;
  if (e >= NE) return;
  float4 a = *reinterpret_cast<const float4*>(&alpha[(size_t)e * 4]);
  int n = idx[e];
  a.x = softplusf((a.x - bnst[8])  * bnst[12] + beta[0]);
  a.y = softplusf((a.y - bnst[9])  * bnst[13] + beta[1]);
  a.z = softplusf((a.z - bnst[10]) * bnst[14] + beta[2]);
  a.w = softplusf((a.w - bnst[11]) * bnst[15] + beta[3]);
  *reinterpret_cast<float4*>(&alpha[(size_t)e * 4]) = a;
  atomicMax(&segmax[n * 4 + 0], __float_as_uint(a.x));
  atomicMax(&segmax[n * 4 + 1], __float_as_uint(a.y));
  atomicMax(&segmax[n * 4 + 2], __float_as_uint(a.z));
  atomicMax(&segmax[n * 4 + 3], __float_as_uint(a.w));
}

// ---------- pass 4: e = exp(a - m); segment sum
__global__ __launch_bounds__(256)
void k_expsum(float* __restrict__ alpha, const int* __restrict__ idx,
              const unsigned* __restrict__ segmax, float* __restrict__ segsum)
{
  int e = blockIdx.x * 256 + threadIdx.x;
  if (e >= NE) return;
  float4 a = *reinterpret_cast<const float4*>(&alpha[(size_t)e * 4]);
  int n = idx[e];
  uint4 m = *reinterpret_cast<const uint4*>(&segmax[n * 4]);
  a.x = expf(a.x - __uint_as_float(m.x));
  a.y = expf(a.y - __uint_as_float(m.y));
  a.z = expf(a.z - __uint_as_float(m.z));
  a.w = expf(a.w - __uint_as_float(m.w));
  *reinterpret_cast<float4*>(&alpha[(size_t)e * 4]) = a;
  atomicAdd(&segsum[n * 4 + 0], a.x);
  atomicAdd(&segsum[n * 4 + 1], a.y);
  atomicAdd(&segsum[n * 4 + 2], a.z);
  atomicAdd(&segsum[n * 4 + 3], a.w);
}

// ---------- pass 5: weighted aggregation into aggr[N,64] (head-mean folded in)
template<int STORE>
__global__ __launch_bounds__(256, 2)
void k_edge_aggr(const float* __restrict__ ea, const float* __restrict__ W,
                 const int* __restrict__ idx, const float* __restrict__ npj,
                 const float* __restrict__ alpha, const float* __restrict__ segsum,
                 const __hip_bfloat16* __restrict__ outj, float* __restrict__ aggr)
{
  __shared__ float Wl[STORE ? 1 : 64][256];
  if (!STORE) {
    for (int t = threadIdx.x; t < 64 * 256; t += 256) Wl[t >> 8][t & 255] = W[16384 + t];
    __syncthreads();
  }
  int wave = threadIdx.x >> 6, lane = threadIdx.x & 63;
  int ebase = blockIdx.x * 64 + wave * 16;
  for (int g = 0; g < 4; ++g) {
    int e0 = ebase + g * 4;
    int ii[4], jj[4];
#pragma unroll
    for (int e = 0; e < 4; ++e) { ii[e] = idx[e0 + e]; jj[e] = idx[NE + e0 + e]; }
    float wgt[4][4];
#pragma unroll
    for (int e = 0; e < 4; ++e) {
      float4 ev = *reinterpret_cast<const float4*>(&alpha[(size_t)(e0 + e) * 4]);
      float4 sv = *reinterpret_cast<const float4*>(&segsum[(size_t)ii[e] * 4]);
      wgt[e][0] = ev.x / (sv.x + 1e-16f);
      wgt[e][1] = ev.y / (sv.y + 1e-16f);
      wgt[e][2] = ev.z / (sv.z + 1e-16f);
      wgt[e][3] = ev.w / (sv.w + 1e-16f);
    }
    float ojv[4][4];
    if (STORE) {
#pragma unroll
      for (int e = 0; e < 4; ++e)
#pragma unroll
        for (int q = 0; q < 4; ++q)
          ojv[e][q] = __bfloat162float(outj[(size_t)(e0 + e) * 256 + lane + 64 * q]);
    } else {
      float ear[4];
#pragma unroll
      for (int e = 0; e < 4; ++e) ear[e] = ea[(size_t)(e0 + e) * 64 + lane];
      float tea[4][4] = {};
      for (int k = 0; k < 64; ++k) {
        float w0 = Wl[k][lane], w1 = Wl[k][lane + 64], w2 = Wl[k][lane + 128], w3 = Wl[k][lane + 192];
#pragma unroll
        for (int e = 0; e < 4; ++e) {
          float a = __shfl(ear[e], k);
          tea[e][0] = fmaf(a, w0, tea[e][0]);
          tea[e][1] = fmaf(a, w1, tea[e][1]);
          tea[e][2] = fmaf(a, w2, tea[e][2]);
          tea[e][3] = fmaf(a, w3, tea[e][3]);
        }
      }
#pragma unroll
      for (int e = 0; e < 4; ++e) {
        size_t bj = (size_t)jj[e] * 256 + lane;
#pragma unroll
        for (int q = 0; q < 4; ++q) ojv[e][q] = softplusf(npj[bj + 64 * q] + tea[e][q]);
      }
    }
#pragma unroll
    for (int e = 0; e < 4; ++e) {
      float c = 0.25f * (ojv[e][0] * wgt[e][0] + ojv[e][1] * wgt[e][1]
                       + ojv[e][2] * wgt[e][2] + ojv[e][3] * wgt[e][3]);
      atomicAdd(&aggr[(size_t)ii[e] * 64 + lane], c);
    }
  }
}

// ---------- pass 6: out = aggr + bias  (f32 output, per reference dtype)
__global__ __launch_bounds__(256)
void k_final(const float* __restrict__ aggr, const float* __restrict__ bias,
             float* __restrict__ out)
{
  int t = blockIdx.x * 256 + threadIdx.x;
  out[t] = aggr[t] + bias[t & 63];
}

extern "C" void kernel_launch(void* const* d_in, const int* in_sizes, int n_in,
                              void* d_out, int out_size, void* d_ws, size_t ws_size,
                              hipStream_t stream)
{
  const float* x    = (const float*)d_in[0];
  const float* ea   = (const float*)d_in[1];
  const float* W    = (const float*)d_in[2];
  const float* att  = (const float*)d_in[3];
  const float* bias = (const float*)d_in[4];
  const float* gam  = (const float*)d_in[5];
  const float* bet  = (const float*)d_in[6];
  const unsigned* idx_raw = (const unsigned*)d_in[7];
  float* out = (float*)d_out;

  char* ws = (char*)d_ws;
  float*    npj    = (float*)(ws + OFF_NPJ);
  float*    alpha  = (float*)(ws + OFF_ALPHA);
  unsigned* segmax = (unsigned*)(ws + OFF_SEGMAX);
  float*    segsum = (float*)(ws + OFF_SEGSUM);
  float*    bnst   = (float*)(ws + OFF_BN);
  unsigned* flag   = (unsigned*)(ws + OFF_BN + 64);
  float*    aggr   = (float*)(ws + OFF_AGGR);
  int*      idx    = (int*)(ws + OFF_IDX32);
  __hip_bfloat16* outj = (__hip_bfloat16*)(ws + OFF_OUTJ);

  hipMemsetAsync(ws + OFF_SEGMAX, 0, Z_SZ, stream);
  k_idx_detect<<<(NE + 255) / 256, 256, 0, stream>>>(idx_raw, flag);
  k_idx_cvt<<<(2 * NE) / 256, 256, 0, stream>>>(idx_raw, flag, idx);
  k_node_proj<<<NN / 4, 256, 0, stream>>>(x, W, npj);

  bool store = ws_size >= NEED_STORE;
  if (store)
    k_edge_alpha<1><<<NE / 64, 256, 0, stream>>>(ea, W, att, idx, npj, alpha, bnst, outj);
  else
    k_edge_alpha<0><<<NE / 64, 256, 0, stream>>>(ea, W, att, idx, npj, alpha, bnst, outj);

  k_bn_fin<<<1, 64, 0, stream>>>(bnst, gam);
  k_bn_max<<<(NE + 255) / 256, 256, 0, stream>>>(alpha, idx, bnst, bet, segmax);
  k_expsum<<<(NE + 255) / 256, 256, 0, stream>>>(alpha, idx, segmax, segsum);

  if (store)
    k_edge_aggr<1><<<NE / 64, 256, 0, stream>>>(ea, W, idx, npj, alpha, segsum, outj, aggr);
  else
    k_edge_aggr<0><<<NE / 64, 256, 0, stream>>>(ea, W, idx, npj, alpha, segsum, outj, aggr);

  k_final<<<(NN * 64) / 256, 256, 0, stream>>>(aggr, bias, out);
}